// Round 4
// baseline (265.539 us; speedup 1.0000x reference)
//
#include <hip/hip_runtime.h>

// DepthwiseTemporalConv: I[n,c,t] = x_flat[n*16384 + c*64 + t], n in [0,4096), c in [0,256), t in [0,64)
// Y[n,c,t] = sum_{k=0}^{63-t} I[n,c,t+k] * W[c,k]
// out_flat[(n>>10)*16777216 + c*65536 + t*1024 + (n&1023)] = Y[n,c,t]
//
// R4: streaming-j form (acc[t] += x[j]*w[j-t]) with asm-pinned x values and
// accumulators. R2/R3 failure mode: compiler rematerialized global loads and
// shed the 64-float array to VGPR=36-40, replaying loads inside the loop.
// An opaque `asm volatile("" : "+v"(v))` def cannot be rematerialized -> the
// 64 accumulators and each loaded x piece must stay in VGPRs. No LDS, no
// barrier; occupancy is VGPR-bound (~85-110 regs -> 4 waves/SIMD).

constexpr int Cc = 256;
constexpr int Tt = 64;
constexpr int Kk = 64;
constexpr int CT = Cc * Tt;   // 16384

__global__ __launch_bounds__(256, 3)
void DepthwiseTemporalConv_24962349924982_kernel(const float* __restrict__ x,
                                                 const float* __restrict__ w,
                                                 float* __restrict__ out) {
    const int tid  = threadIdx.x;
    const int lane = tid & 63;
    const int wv   = tid >> 6;

    const int n_tile = blockIdx.x & 63;   // 64 n-tiles
    const int c_tile = blockIdx.x >> 6;   // 64 c-tiles
    const int n  = n_tile * 64 + lane;
    const int cv = c_tile * 4 + wv;

    // ---- weights: wave-uniform address -> scalar loads into SGPRs
    const int cu = __builtin_amdgcn_readfirstlane(cv);
    const float* __restrict__ wp = w + (size_t)cu * Kk;
    float wr[Kk];
    #pragma unroll
    for (int m = 0; m < 16; ++m) {
        const float4 v = *(const float4*)(wp + 4 * m);
        wr[4*m+0] = v.x; wr[4*m+1] = v.y; wr[4*m+2] = v.z; wr[4*m+3] = v.w;
    }

    // ---- 64 accumulators, pinned: opaque asm def is non-rematerializable,
    // so the compiler must keep them resident (or visibly spill — it won't,
    // peak live ~85 < cap 170).
    float acc[Tt];
    #pragma unroll
    for (int t = 0; t < Tt; ++t) {
        acc[t] = 0.f;
        asm volatile("" : "+v"(acc[t]));
    }

    // ---- stream this thread's contiguous 256B row, one float4 at a time.
    // Pin each loaded piece so it cannot be re-loaded later (defeats the
    // loop-interchange + remat transform that killed R2/R3).
    const float4* __restrict__ rp =
        (const float4*)(x + (size_t)n * CT + (size_t)cu * Tt);
    #pragma unroll
    for (int m = 0; m < 16; ++m) {
        float4 v = rp[m];
        asm volatile("" : "+v"(v.x), "+v"(v.y), "+v"(v.z), "+v"(v.w));
        const float e[4] = {v.x, v.y, v.z, v.w};
        #pragma unroll
        for (int q = 0; q < 4; ++q) {
            const int j = 4 * m + q;
            const float xv = e[q];
            #pragma unroll
            for (int t = 0; t <= j; ++t)
                acc[t] = fmaf(xv, wr[j - t], acc[t]);
        }
    }

    // ---- store: wave-coalesced (lane -> consecutive n; 256B/instr/wave)
    float* __restrict__ obase = out + (size_t)(n >> 10) * (Cc * Tt * 1024)
                                    + (size_t)cv * (Tt * 1024) + (n & 1023);
    #pragma unroll
    for (int t = 0; t < Tt; ++t)
        obase[(size_t)t * 1024] = acc[t];
}

extern "C" void kernel_launch(void* const* d_in, const int* in_sizes, int n_in,
                              void* d_out, int out_size, void* d_ws, size_t ws_size,
                              hipStream_t stream) {
    const float* x = (const float*)d_in[0];
    const float* w = (const float*)d_in[1];
    float* out = (float*)d_out;
    DepthwiseTemporalConv_24962349924982_kernel<<<dim3(4096), dim3(256), 0, stream>>>(x, w, out);
}

// Round 5
// 147.875 us; speedup vs baseline: 1.7957x; 1.7957x over previous
//
#include <hip/hip_runtime.h>

// DepthwiseTemporalConv: I[n,c,t] = x_flat[n*16384 + c*64 + t], n in [0,4096), c in [0,256), t in [0,64)
// Y[n,c,t] = sum_{k=0}^{63-t} I[n,c,t+k] * W[c,k]
// out_flat[(n>>10)*16777216 + c*65536 + t*1024 + (n&1023)] = Y[n,c,t]
//
// R5: one wave per block, 64 n x 1 c per wave. Wave stages its own 16 KiB via
// 16 global_load_lds (per-lane global src gathers 4 strided 256B rows into a
// linear 1 KiB LDS chunk), wave-local vmcnt(0) -- NO barrier, waves fully
// independent -> 9 blocks/CU all free-running (R1 was 2 blocks/CU with a
// block-wide stage->barrier->compute serialization). LDS-sourced xr[64] is the
// one structure hipcc compiles faithfully (R1: VGPR=88; global-sourced arrays
// get rematerialized (R2/R3) or spilled (R4)). c comes from blockIdx -> weights
// are compile-time-uniform -> SGPRs.

constexpr int Cc = 256;
constexpr int Tt = 64;
constexpr int Kk = 64;
constexpr int CT = Cc * Tt;               // 16384
constexpr int CHUNK_STRIDE = 1024 + 16;   // per-gload_lds 1 KiB chunk + pad
constexpr int LDS_BYTES = 16 * CHUNK_STRIDE;  // 16640 B -> 9 blocks/CU

__global__ __launch_bounds__(64, 2)
void DepthwiseTemporalConv_24962349924982_kernel(const float* __restrict__ x,
                                                 const float* __restrict__ w,
                                                 float* __restrict__ out) {
    __shared__ __align__(16) char lds[LDS_BYTES];
    const int lane = threadIdx.x & 63;

    const int n_tile = blockIdx.x & 63;   // 4096/64 n-tiles
    const int c      = blockIdx.x >> 6;   // 256 c values (block-uniform -> SGPR)
    const int n0 = n_tile * 64;
    const int n  = n0 + lane;

    // ---- stage: instr i gathers rows n0+4i..n0+4i+3 (each 256 B, 16-KB apart
    // in global; per-lane src addresses) into a linear 1 KiB LDS chunk.
    // Lane l -> row n0+4i+(l>>4), bytes (l&15)*16..+16.
    #pragma unroll
    for (int i = 0; i < 16; ++i) {
        const float* gsrc = x + (size_t)(n0 + 4 * i + (lane >> 4)) * CT
                              + (size_t)c * Tt + (lane & 15) * 4;
        __builtin_amdgcn_global_load_lds(
            (const __attribute__((address_space(1))) void*)gsrc,
            (__attribute__((address_space(3))) void*)(lds + i * CHUNK_STRIDE),
            16, 0, 0);
    }

    // ---- weights: block-uniform c -> scalar loads into SGPRs
    float wr[Kk];
    {
        const float4* wp = (const float4*)(w + (size_t)c * Kk);
        #pragma unroll
        for (int m = 0; m < 16; ++m) {
            const float4 v = wp[m];
            wr[4*m+0] = v.x; wr[4*m+1] = v.y; wr[4*m+2] = v.z; wr[4*m+3] = v.w;
        }
    }

    // wave-local drain of the global_load_lds queue; no s_barrier needed
    // (this block is a single wave). "memory" clobber orders the ds_reads.
    asm volatile("s_waitcnt vmcnt(0)" ::: "memory");
    __builtin_amdgcn_sched_barrier(0);

    // ---- this lane's row (n = n0+lane): chunk l>>2, slot l&3.
    // Bank quad = ((l>>2)+m) mod 8 -> 4-way conflict per 16-lane phase
    // (~1.6x on ~12cy b128 = ~300 cy total; negligible vs 4160 cy FMA).
    float xr[Tt];
    {
        const char* base = lds + (lane >> 2) * CHUNK_STRIDE + (lane & 3) * 256;
        #pragma unroll
        for (int m = 0; m < 16; ++m) {
            const float4 v = *(const float4*)(base + m * 16);
            xr[4*m+0] = v.x; xr[4*m+1] = v.y; xr[4*m+2] = v.z; xr[4*m+3] = v.w;
        }
    }

    // ---- triangular suffix correlation (R1 structure — compiles faithfully),
    // 2 accumulator chains; stores are 256 B contiguous per (c,t) per wave.
    float* __restrict__ obase = out + (size_t)(n >> 10) * (Cc * Tt * 1024)
                                    + (size_t)c * (Tt * 1024) + (n & 1023);
    #pragma unroll
    for (int t = 0; t < Tt; ++t) {
        const int len = Tt - t;
        float a0 = 0.f, a1 = 0.f;
        #pragma unroll
        for (int k = 0; k + 1 < len; k += 2) {
            a0 = fmaf(xr[t + k],     wr[k],     a0);
            a1 = fmaf(xr[t + k + 1], wr[k + 1], a1);
        }
        if (len & 1) a0 = fmaf(xr[Tt - 1], wr[len - 1], a0);
        obase[(size_t)t * 1024] = a0 + a1;
    }
}

extern "C" void kernel_launch(void* const* d_in, const int* in_sizes, int n_in,
                              void* d_out, int out_size, void* d_ws, size_t ws_size,
                              hipStream_t stream) {
    const float* x = (const float*)d_in[0];
    const float* w = (const float*)d_in[1];
    float* out = (float*)d_out;
    // 64 n-tiles x 256 c = 16384 single-wave blocks
    DepthwiseTemporalConv_24962349924982_kernel<<<dim3(16384), dim3(64), 0, stream>>>(x, w, out);
}